// Round 2
// baseline (398.556 us; speedup 1.0000x reference)
//
#include <hip/hip_runtime.h>
#include <hip/hip_bf16.h>
#include <math.h>

namespace {

constexpr int NTOK   = 4096;   // B*T
constexpr int DDIM   = 1024;
constexpr int E      = 8;
constexpr int HDIM   = 2048;
constexpr int MAXROWS = 8192;  // NTOK * K (every token -> exactly 2 rows)
constexpr int MAXMB   = 40;    // 256-row m-tiles: sum_e ceil(cnt_e/256) <= 32+7=39; 40 = 8*5

typedef __bf16 bf16;
typedef __attribute__((ext_vector_type(4))) __bf16 bf16x4;
typedef __attribute__((ext_vector_type(8))) __bf16 bf16x8;
typedef __attribute__((ext_vector_type(4))) float floatx4;
typedef __attribute__((ext_vector_type(4))) int   i32x4;

// async global->LDS, 16B per lane; LDS dest = WAVE-UNIFORM base, HW adds lane*16
__device__ inline void gload_lds16(const bf16* g, bf16* l) {
  __builtin_amdgcn_global_load_lds(
      (const __attribute__((address_space(1))) void*)g,
      (__attribute__((address_space(3))) void*)l, 16, 0, 0);
}

// inline-asm ds_read_b128: invisible to the waitcnt pass (no conservative vmcnt(0)
// drain of in-flight prefetch). Discipline: explicit lgkmcnt(0) + sched_barrier(0)
// before consuming MFMAs (rule #18).
__device__ inline bf16x8 ds_read16(const bf16* p) {
  i32x4 r;
  asm volatile("ds_read_b128 %0, %1"
               : "=v"(r)
               : "v"((const __attribute__((address_space(3))) bf16*)p));
  return __builtin_bit_cast(bf16x8, r);
}

// ---------------- init: zero strided counts region (128 ints = 512B) ----------------
__global__ void init_kernel(int* counts) {
  counts[threadIdx.x] = 0;   // 128 threads
}

// ------- router: fp32 logits -> top2 + gates; fused bf16 cast of x -------
__global__ void router_kernel(const float* __restrict__ x,
                              const float* __restrict__ Wr,
                              const float* __restrict__ br,
                              int* __restrict__ counts,     // stride 16 ints per expert
                              int* __restrict__ topk_e,
                              float* __restrict__ topk_g,
                              bf16* __restrict__ xb) {
  int wave = threadIdx.x >> 6;
  int lane = threadIdx.x & 63;
  int t0 = (blockIdx.x * 4 + wave) * 2;   // grid = NTOK/8, exact

  float acc[16];
#pragma unroll
  for (int j = 0; j < 16; ++j) acc[j] = 0.f;

#pragma unroll
  for (int i = 0; i < DDIM / 64; ++i) {
    int d = i * 64 + lane;
    float4 w0 = *(const float4*)(Wr + (size_t)d * E);
    float4 w1 = *(const float4*)(Wr + (size_t)d * E + 4);
#pragma unroll
    for (int t = 0; t < 2; ++t) {
      float xv = x[(size_t)(t0 + t) * DDIM + d];
      xb[(size_t)(t0 + t) * DDIM + d] = (bf16)xv;
      acc[t * 8 + 0] += xv * w0.x; acc[t * 8 + 1] += xv * w0.y;
      acc[t * 8 + 2] += xv * w0.z; acc[t * 8 + 3] += xv * w0.w;
      acc[t * 8 + 4] += xv * w1.x; acc[t * 8 + 5] += xv * w1.y;
      acc[t * 8 + 6] += xv * w1.z; acc[t * 8 + 7] += xv * w1.w;
    }
  }
#pragma unroll
  for (int off = 32; off > 0; off >>= 1) {
#pragma unroll
    for (int j = 0; j < 16; ++j) acc[j] += __shfl_xor(acc[j], off, 64);
  }
  if (lane == 0) {
#pragma unroll
    for (int t = 0; t < 2; ++t) {
      int tt = t0 + t;
      float lg[E];
#pragma unroll
      for (int e = 0; e < E; ++e) lg[e] = acc[t * 8 + e] + br[e];
      int e0 = 0;
#pragma unroll
      for (int e = 1; e < E; ++e) if (lg[e] > lg[e0]) e0 = e;
      int e1 = (e0 == 0) ? 1 : 0;
#pragma unroll
      for (int e = 0; e < E; ++e) if (e != e0 && lg[e] > lg[e1]) e1 = e;
      float ex = expf(lg[e1] - lg[e0]);
      float s = 1.f + ex;
      topk_e[2 * tt]     = e0;
      topk_e[2 * tt + 1] = e1;
      topk_g[2 * tt]     = 1.f / s;
      topk_g[2 * tt + 1] = ex / s;
      atomicAdd(&counts[e0 * 16], 1);
      atomicAdd(&counts[e1 * 16], 1);
    }
  }
}

// ------- scan: offsets + cursors + compact block map (256-row tiles) -------
__global__ void scan_kernel(const int* __restrict__ counts,   // stride 16
                            int* __restrict__ offsets,
                            int* __restrict__ cursor,          // stride 16
                            int* __restrict__ blockmap,        // [MAXMB] packed e<<16|mtile
                            int* __restrict__ nblk) {
  if (threadIdx.x == 0 && blockIdx.x == 0) {
    int s = 0, nb = 0;
    for (int e = 0; e < E; ++e) {
      offsets[e] = s; cursor[e * 16] = s;
      int c = counts[e * 16];
      int nt = (c + 255) >> 8;
      for (int m = 0; m < nt; ++m) blockmap[nb++] = (e << 16) | m;
      s += c;
    }
    offsets[E] = s;
    nblk[0] = nb;
  }
}

// ------- scatter: wave-aggregated cursor atomics -------
__global__ void scatter_kernel(const int* __restrict__ topk_e,
                               int* __restrict__ cursor,       // stride 16
                               int* __restrict__ rowtok,
                               int* __restrict__ tokrow) {
  int t = blockIdx.x * 256 + threadIdx.x;   // grid = NTOK/256, exact
  int lane = threadIdx.x & 63;
  unsigned long long lt = ((unsigned long long)1 << lane) - 1;
#pragma unroll
  for (int k = 0; k < 2; ++k) {
    int e = topk_e[2 * t + k];
#pragma unroll
    for (int ee = 0; ee < E; ++ee) {
      unsigned long long m = __ballot(e == ee);
      if (m) {
        int leader = __ffsll((long long)m) - 1;
        int base = 0;
        if (lane == leader) base = atomicAdd(&cursor[ee * 16], __popcll(m));
        base = __shfl(base, leader, 64);
        if (e == ee) {
          int row = base + __popcll(m & lt);
          rowtok[row] = t;
          tokrow[2 * t + k] = row;
        }
      }
    }
  }
}

// -------- batched transpose+cast: fp32 in [batch][R][C] -> bf16 out [batch][C][R] --------
__global__ void transpose_cast_kernel(const float* __restrict__ in, bf16* __restrict__ out,
                                      int R, int C) {
  __shared__ bf16 tile[64][72];
  const float* src = in + (size_t)blockIdx.z * R * C;
  bf16* dst = out + (size_t)blockIdx.z * R * C;
  int c0 = blockIdx.x * 64, r0 = blockIdx.y * 64;
  int tr = threadIdx.x >> 4;          // 0..15
  int tc = (threadIdx.x & 15) * 4;    // 0..60
#pragma unroll
  for (int i = 0; i < 4; ++i) {
    int r = tr + i * 16;
    float4 v = *(const float4*)(src + (size_t)(r0 + r) * C + c0 + tc);
    bf16x4 o;
    o[0] = (bf16)v.x; o[1] = (bf16)v.y; o[2] = (bf16)v.z; o[3] = (bf16)v.w;
    *(bf16x4*)&tile[r][tc] = o;
  }
  __syncthreads();
  int tr2 = threadIdx.x >> 3;         // 0..31
  int tc2 = (threadIdx.x & 7) * 8;    // 0..56
#pragma unroll
  for (int i = 0; i < 2; ++i) {
    int c = tr2 + i * 32;
    bf16x8 v;
#pragma unroll
    for (int j = 0; j < 8; ++j) v[j] = tile[tc2 + j][c];
    *(bf16x8*)(dst + (size_t)(c0 + c) * R + r0 + tc2) = v;
  }
}

// ================= grouped FFN GEMM: 256x256 8-wave 4-phase/K-tile pipeline =============
// Template geometry (guide §5 "8-phase"): BM=256, BN=256, BK=64, 512 thr = 8 waves
// (2m x 4n), per-wave output 128x64, LDS = 2dbuf x 2khalf x 256 x 32 x (A,B) = 128 KB.
// Staging granularity = k-half (256 rows x 32k = 16 KB = 2 gload_lds16/thread), order
// per K-tile: Ak0,Bk0,Ak1,Bk1, always into buf[(t+1)&1] (never the live buffer).
// Counted waits, each followed by s_barrier before dependent cross-wave ds_reads:
//   end of phase 3 of t: vmcnt(4) -> Ak0,Bk0(t+1) landed (4 younger = Ak1,Bk1(t+1))
//   end of phase 1 of t: vmcnt(4) -> Ak1,Bk1(t)  landed (4 younger = Ak0,Bk0(t+1))
// Loads land >= 4 phases (~800 cyc) after issue; never vmcnt(0) except the final tile.
template <bool GATHER, bool RELU>
__global__ __launch_bounds__(512, 2) void ffn_gemm(
    const bf16* __restrict__ A, const bf16* __restrict__ W,
    const float* __restrict__ bias, bf16* __restrict__ Y,
    const int* __restrict__ rowtok, const int* __restrict__ offsets,
    const int* __restrict__ counts,   // stride 16
    const int* __restrict__ blockmap, const int* __restrict__ nblk,
    int Kdim, int Ndim) {
  // T1: bijective XCD remap. grid = (MAXMB, NY), MAXMB=40 (8|40). Each XCD owns
  // whole n-strip(s) and sweeps m, so its 512KB W panel stays L2-resident.
  int NY  = Ndim >> 8;                 // 8 (GEMM1) or 4 (GEMM2)
  int xcd = blockIdx.x & 7;
  int local = blockIdx.y * (MAXMB / 8) + (blockIdx.x >> 3);  // [0, 5*NY)
  int gpx = 8 / NY;                    // XCD groups per n-strip (1 or 2)
  int nIdx = xcd / gpx;
  int mIdx = (xcd % gpx) * (MAXMB / gpx) + local;
  if (mIdx >= nblk[0]) return;
  int bm = blockmap[mIdx];
  int e = bm >> 16;
  int mBase = (bm & 0xffff) << 8;      // 256-row tiles
  int cnt = counts[e * 16];
  int rowBase = offsets[e] + mBase;
  int nBase = nIdx << 8;
  int validRows = cnt - mBase; if (validRows > 256) validRows = 256;

  __shared__ bf16 Asm[2][2][256][32];  // [dbuf][khalf][row][k]  64 KB
  __shared__ bf16 Bsm[2][2][256][32];  //                        64 KB

  int tid = threadIdx.x;
  int wave = tid >> 6, lane = tid & 63;

  // ---- staging addressing: thread covers rows (tid>>2) and (tid>>2)+128, seg tid&3.
  // T2 both-sides swizzle: source k-seg = seg ^ (row&3); LDS dest stays linear
  // (gload_lds writes uniform-base + lane*16). (row+128)&3 == row&3 -> one swz.
  int srow = tid >> 2;                 // 0..127
  int sseg = tid & 3;
  int swz  = sseg ^ (srow & 3);

  const bf16 *aR0, *aR1, *bR0, *bR1;
  {
    int r0 = rowBase + srow, r1 = rowBase + srow + 128;
    if (r0 > MAXROWS - 1) r0 = MAXROWS - 1;   // partial tile: dup row, masked at store
    if (r1 > MAXROWS - 1) r1 = MAXROWS - 1;
    size_t ro0 = GATHER ? (size_t)rowtok[r0] * Kdim : (size_t)r0 * Kdim;
    size_t ro1 = GATHER ? (size_t)rowtok[r1] * Kdim : (size_t)r1 * Kdim;
    aR0 = A + ro0 + swz * 8;
    aR1 = A + ro1 + swz * 8;
    size_t wb = (size_t)e * Ndim;
    bR0 = W + (wb + nBase + srow) * (size_t)Kdim + swz * 8;
    bR1 = W + (wb + nBase + srow + 128) * (size_t)Kdim + swz * 8;
  }

  auto stageA = [&](int d, int kh, int kb) {   // kb = absolute k of the half
    bf16* l = &Asm[d][kh][0][0] + wave * 512;
    gload_lds16(aR0 + kb, l);
    gload_lds16(aR1 + kb, l + 4096);
  };
  auto stageB = [&](int d, int kh, int kb) {
    bf16* l = &Bsm[d][kh][0][0] + wave * 512;
    gload_lds16(bR0 + kb, l);
    gload_lds16(bR1 + kb, l + 4096);
  };

  // ---- fragment addressing (read-side XOR = same involution as source swizzle)
  int wm2 = wave >> 2;                 // 0..1  m-half of block (wave's 128 rows)
  int wn2 = wave & 3;                  // 0..3  n-quarter (wave's 64 cols)
  int frow = lane & 15;
  int rseg = (((lane >> 4) ^ (lane & 3)) << 3);  // element offset within 32-k row

  floatx4 acc[8][4];
#pragma unroll
  for (int m = 0; m < 8; ++m)
#pragma unroll
    for (int n = 0; n < 4; ++n) acc[m][n] = floatx4{0.f, 0.f, 0.f, 0.f};

  int nkt = Kdim >> 6;

  // ---- prologue: stage K-tile 0 into buf 0 (issue order Ak0,Bk0,Ak1,Bk1 = 8 loads)
  stageA(0, 0, 0); stageB(0, 0, 0); stageA(0, 1, 32); stageB(0, 1, 32);
  asm volatile("s_waitcnt vmcnt(4)" ::: "memory");   // Ak0,Bk0(0) landed
  asm volatile("s_barrier" ::: "memory");

  bf16x8 af[4], bfr[4];
  int d = 0;
  for (int kt = 0; kt < nkt; ++kt) {
    bool more = (kt + 1 < nkt);
    int kb = (kt + 1) << 6;            // next K-tile base k

    // ---------- phase 0: kh=0, m 0..3 ----------
#pragma unroll
    for (int n = 0; n < 4; ++n)
      bfr[n] = ds_read16(&Bsm[d][0][wn2 * 64 + n * 16 + frow][0] + rseg);
#pragma unroll
    for (int m = 0; m < 4; ++m)
      af[m] = ds_read16(&Asm[d][0][wm2 * 128 + m * 16 + frow][0] + rseg);
    if (more) stageA(d ^ 1, 0, kb);
    asm volatile("s_barrier" ::: "memory");
    asm volatile("s_waitcnt lgkmcnt(0)" ::: "memory");
    __builtin_amdgcn_sched_barrier(0);
    __builtin_amdgcn_s_setprio(1);
#pragma unroll
    for (int m = 0; m < 4; ++m)
#pragma unroll
      for (int n = 0; n < 4; ++n)
        acc[m][n] = __builtin_amdgcn_mfma_f32_16x16x32_bf16(af[m], bfr[n], acc[m][n], 0, 0, 0);
    __builtin_amdgcn_s_setprio(0);
    asm volatile("s_barrier" ::: "memory");

    // ---------- phase 1: kh=0, m 4..7 ----------
#pragma unroll
    for (int m = 0; m < 4; ++m)
      af[m] = ds_read16(&Asm[d][0][wm2 * 128 + (m + 4) * 16 + frow][0] + rseg);
    if (more) stageB(d ^ 1, 0, kb);
    asm volatile("s_barrier" ::: "memory");
    asm volatile("s_waitcnt lgkmcnt(0)" ::: "memory");
    __builtin_amdgcn_sched_barrier(0);
    __builtin_amdgcn_s_setprio(1);
#pragma unroll
    for (int m = 0; m < 4; ++m)
#pragma unroll
      for (int n = 0; n < 4; ++n)
        acc[m + 4][n] = __builtin_amdgcn_mfma_f32_16x16x32_bf16(af[m], bfr[n], acc[m + 4][n], 0, 0, 0);
    __builtin_amdgcn_s_setprio(0);
    if (more) asm volatile("s_waitcnt vmcnt(4)" ::: "memory");  // Ak1,Bk1(t) landed
    else      asm volatile("s_waitcnt vmcnt(0)" ::: "memory");  // last tile: drain them
    asm volatile("s_barrier" ::: "memory");

    // ---------- phase 2: kh=1, m 0..3 ----------
#pragma unroll
    for (int n = 0; n < 4; ++n)
      bfr[n] = ds_read16(&Bsm[d][1][wn2 * 64 + n * 16 + frow][0] + rseg);
#pragma unroll
    for (int m = 0; m < 4; ++m)
      af[m] = ds_read16(&Asm[d][1][wm2 * 128 + m * 16 + frow][0] + rseg);
    if (more) stageA(d ^ 1, 1, kb + 32);
    asm volatile("s_barrier" ::: "memory");
    asm volatile("s_waitcnt lgkmcnt(0)" ::: "memory");
    __builtin_amdgcn_sched_barrier(0);
    __builtin_amdgcn_s_setprio(1);
#pragma unroll
    for (int m = 0; m < 4; ++m)
#pragma unroll
      for (int n = 0; n < 4; ++n)
        acc[m][n] = __builtin_amdgcn_mfma_f32_16x16x32_bf16(af[m], bfr[n], acc[m][n], 0, 0, 0);
    __builtin_amdgcn_s_setprio(0);
    asm volatile("s_barrier" ::: "memory");

    // ---------- phase 3: kh=1, m 4..7 ----------
#pragma unroll
    for (int m = 0; m < 4; ++m)
      af[m] = ds_read16(&Asm[d][1][wm2 * 128 + (m + 4) * 16 + frow][0] + rseg);
    if (more) stageB(d ^ 1, 1, kb + 32);
    asm volatile("s_barrier" ::: "memory");
    asm volatile("s_waitcnt lgkmcnt(0)" ::: "memory");
    __builtin_amdgcn_sched_barrier(0);
    __builtin_amdgcn_s_setprio(1);
#pragma unroll
    for (int m = 0; m < 4; ++m)
#pragma unroll
      for (int n = 0; n < 4; ++n)
        acc[m + 4][n] = __builtin_amdgcn_mfma_f32_16x16x32_bf16(af[m], bfr[n], acc[m + 4][n], 0, 0, 0);
    __builtin_amdgcn_s_setprio(0);
    if (more) asm volatile("s_waitcnt vmcnt(4)" ::: "memory");  // Ak0,Bk0(t+1) landed
    asm volatile("s_barrier" ::: "memory");
    d ^= 1;
  }

  // epilogue: C/D layout col=lane&15, row=(lane>>4)*4+reg  [m89-verified]
  int crow = (lane >> 4) * 4;
  int ccol = lane & 15;
#pragma unroll
  for (int n = 0; n < 4; ++n) {
    int colg = nBase + wn2 * 64 + n * 16 + ccol;
    float bv = bias[(size_t)e * Ndim + colg];
#pragma unroll
    for (int m = 0; m < 8; ++m) {
#pragma unroll
      for (int r = 0; r < 4; ++r) {
        int rl = wm2 * 128 + m * 16 + crow + r;
        if (rl < validRows) {
          float v = acc[m][n][r] + bv;
          if (RELU) v = fmaxf(v, 0.f);
          Y[(size_t)(rowBase + rl) * Ndim + colg] = (bf16)v;
        }
      }
    }
  }
}

// ---------------- combine: out[t] = g0*Y2[r0] + g1*Y2[r1]  (fp32 out) ----------------
__global__ void combine_kernel(const bf16* __restrict__ Y2,
                               const int* __restrict__ tokrow,
                               const float* __restrict__ topk_g,
                               float* __restrict__ out) {
  int idx = blockIdx.x * 256 + threadIdx.x;
  int t = idx >> 7;              // DDIM/8 = 128 vectors per token
  int d8 = (idx & 127) * 8;
  int r0 = tokrow[2 * t], r1 = tokrow[2 * t + 1];
  float g0 = topk_g[2 * t], g1 = topk_g[2 * t + 1];
  bf16x8 a = *(const bf16x8*)(Y2 + (size_t)r0 * DDIM + d8);
  bf16x8 b = *(const bf16x8*)(Y2 + (size_t)r1 * DDIM + d8);
  float o[8];
#pragma unroll
  for (int j = 0; j < 8; ++j) o[j] = g0 * (float)a[j] + g1 * (float)b[j];
  float* op = out + (size_t)t * DDIM + d8;
  *(float4*)op = *(float4*)&o[0];
  *(float4*)(op + 4) = *(float4*)&o[4];
}

}  // namespace

extern "C" void kernel_launch(void* const* d_in, const int* in_sizes, int n_in,
                              void* d_out, int out_size, void* d_ws, size_t ws_size,
                              hipStream_t stream) {
  const float* x  = (const float*)d_in[0];   // [B,T,D] fp32
  const float* Wr = (const float*)d_in[1];   // [D,E]   fp32
  const float* br = (const float*)d_in[2];   // [E]     fp32
  const float* W1 = (const float*)d_in[3];   // [E,D,H] fp32
  const float* b1 = (const float*)d_in[4];   // [E,H]   fp32
  const float* W2 = (const float*)d_in[5];   // [E,H,D] fp32
  const float* b2 = (const float*)d_in[6];   // [E,D]   fp32
  float* out = (float*)d_out;                // [B,T,D] fp32

  char* w = (char*)d_ws;
  int*   counts   = (int*)(w);               // 8 experts, stride 16 ints (64B apart)
  int*   cursor   = (int*)(w + 512);         // 8 experts, stride 16 ints
  int*   offsets  = (int*)(w + 1024);        // 9 ints
  int*   blockmap = (int*)(w + 2048);        // 40 ints
  int*   nblk     = (int*)(w + 2048 + 512);
  int*   topk_e   = (int*)(w + 4096);
  float* topk_g   = (float*)(w + 4096 + 32768);
  int*   rowtok   = (int*)(w + 4096 + 65536);
  int*   tokrow   = (int*)(w + 4096 + 98304);
  char*  big      = w + 4096 + 131072;
  bf16* xb  = (bf16*)(big);                        // [4096][D]  bf16   8.4 MB
  bf16* W1T = (bf16*)(big + 8388608);              // [E][H][D]  bf16  33.5 MB
  bf16* W2T = (bf16*)(big + 8388608 + 33554432);   // [E][D][H]  bf16  33.5 MB
  bf16* Y1  = (bf16*)(big + 8388608 + 67108864);   // [8192][H]  bf16  33.5 MB
  bf16* Y2  = (bf16*)(big + 8388608);              // alias W1T (dead after GEMM1)

  init_kernel<<<1, 128, 0, stream>>>(counts);
  transpose_cast_kernel<<<dim3(HDIM / 64, DDIM / 64, E), 256, 0, stream>>>(W1, W1T, DDIM, HDIM);
  transpose_cast_kernel<<<dim3(DDIM / 64, HDIM / 64, E), 256, 0, stream>>>(W2, W2T, HDIM, DDIM);
  router_kernel<<<NTOK / 8, 256, 0, stream>>>(x, Wr, br, counts, topk_e, topk_g, xb);
  scan_kernel<<<1, 1, 0, stream>>>(counts, offsets, cursor, blockmap, nblk);
  scatter_kernel<<<NTOK / 256, 256, 0, stream>>>(topk_e, cursor, rowtok, tokrow);
  ffn_gemm<true, true><<<dim3(MAXMB, HDIM / 256), 512, 0, stream>>>(
      xb, W1T, b1, Y1, rowtok, offsets, counts, blockmap, nblk, DDIM, HDIM);
  ffn_gemm<false, false><<<dim3(MAXMB, DDIM / 256), 512, 0, stream>>>(
      Y1, W2T, b2, Y2, rowtok, offsets, counts, blockmap, nblk, HDIM, DDIM);
  combine_kernel<<<NTOK * DDIM / 8 / 256, 256, 0, stream>>>(Y2, tokrow, topk_g, out);
}

// Round 3
// 377.455 us; speedup vs baseline: 1.0559x; 1.0559x over previous
//
#include <hip/hip_runtime.h>
#include <hip/hip_bf16.h>
#include <math.h>

namespace {

constexpr int NTOK   = 4096;   // B*T
constexpr int DDIM   = 1024;
constexpr int E      = 8;
constexpr int HDIM   = 2048;
constexpr int MAXROWS = 8192;  // NTOK * K (every token -> exactly 2 rows)
constexpr int MAXBLK  = 72;    // >= sum_e ceil(cnt_e/128) <= 64+7; 72 = 8*9 (XCD-clean)

typedef __bf16 bf16;
typedef __attribute__((ext_vector_type(4))) __bf16 bf16x4;
typedef __attribute__((ext_vector_type(8))) __bf16 bf16x8;
typedef __attribute__((ext_vector_type(4))) float floatx4;
typedef __attribute__((ext_vector_type(4))) int   i32x4;

// async global->LDS, 16B per lane; LDS dest = WAVE-UNIFORM base, HW adds lane*16
__device__ inline void gload_lds16(const bf16* g, bf16* l) {
  __builtin_amdgcn_global_load_lds(
      (const __attribute__((address_space(1))) void*)g,
      (__attribute__((address_space(3))) void*)l, 16, 0, 0);
}

// inline-asm ds_read_b128: invisible to the waitcnt pass (no conservative vmcnt(0)
// drain of in-flight prefetch). Discipline: explicit lgkmcnt(0) + sched_barrier(0)
// before consuming MFMAs (rule #18).
__device__ inline bf16x8 ds_read16(const bf16* p) {
  i32x4 r;
  asm volatile("ds_read_b128 %0, %1"
               : "=v"(r)
               : "v"((const __attribute__((address_space(3))) bf16*)p));
  return __builtin_bit_cast(bf16x8, r);
}

// ---------------- init: zero strided counts region (128 ints = 512B) ----------------
__global__ void init_kernel(int* counts) {
  counts[threadIdx.x] = 0;   // 128 threads
}

// ------- router: fp32 logits -> top2 + gates; fused bf16 cast of x -------
__global__ void router_kernel(const float* __restrict__ x,
                              const float* __restrict__ Wr,
                              const float* __restrict__ br,
                              int* __restrict__ counts,     // stride 16 ints per expert
                              int* __restrict__ topk_e,
                              float* __restrict__ topk_g,
                              bf16* __restrict__ xb) {
  int wave = threadIdx.x >> 6;
  int lane = threadIdx.x & 63;
  int t0 = (blockIdx.x * 4 + wave) * 2;   // grid = NTOK/8, exact

  float acc[16];
#pragma unroll
  for (int j = 0; j < 16; ++j) acc[j] = 0.f;

#pragma unroll
  for (int i = 0; i < DDIM / 64; ++i) {
    int d = i * 64 + lane;
    float4 w0 = *(const float4*)(Wr + (size_t)d * E);
    float4 w1 = *(const float4*)(Wr + (size_t)d * E + 4);
#pragma unroll
    for (int t = 0; t < 2; ++t) {
      float xv = x[(size_t)(t0 + t) * DDIM + d];
      xb[(size_t)(t0 + t) * DDIM + d] = (bf16)xv;
      acc[t * 8 + 0] += xv * w0.x; acc[t * 8 + 1] += xv * w0.y;
      acc[t * 8 + 2] += xv * w0.z; acc[t * 8 + 3] += xv * w0.w;
      acc[t * 8 + 4] += xv * w1.x; acc[t * 8 + 5] += xv * w1.y;
      acc[t * 8 + 6] += xv * w1.z; acc[t * 8 + 7] += xv * w1.w;
    }
  }
#pragma unroll
  for (int off = 32; off > 0; off >>= 1) {
#pragma unroll
    for (int j = 0; j < 16; ++j) acc[j] += __shfl_xor(acc[j], off, 64);
  }
  if (lane == 0) {
#pragma unroll
    for (int t = 0; t < 2; ++t) {
      int tt = t0 + t;
      float lg[E];
#pragma unroll
      for (int e = 0; e < E; ++e) lg[e] = acc[t * 8 + e] + br[e];
      int e0 = 0;
#pragma unroll
      for (int e = 1; e < E; ++e) if (lg[e] > lg[e0]) e0 = e;
      int e1 = (e0 == 0) ? 1 : 0;
#pragma unroll
      for (int e = 0; e < E; ++e) if (e != e0 && lg[e] > lg[e1]) e1 = e;
      float ex = expf(lg[e1] - lg[e0]);
      float s = 1.f + ex;
      topk_e[2 * tt]     = e0;
      topk_e[2 * tt + 1] = e1;
      topk_g[2 * tt]     = 1.f / s;
      topk_g[2 * tt + 1] = ex / s;
      atomicAdd(&counts[e0 * 16], 1);
      atomicAdd(&counts[e1 * 16], 1);
    }
  }
}

// ------- scan: offsets + cursors + compact block map (128-row tiles) -------
__global__ void scan_kernel(const int* __restrict__ counts,   // stride 16
                            int* __restrict__ offsets,
                            int* __restrict__ cursor,          // stride 16
                            int* __restrict__ blockmap,        // [MAXBLK] packed e<<16|mtile
                            int* __restrict__ nblk) {
  if (threadIdx.x == 0 && blockIdx.x == 0) {
    int s = 0, nb = 0;
    for (int e = 0; e < E; ++e) {
      offsets[e] = s; cursor[e * 16] = s;
      int c = counts[e * 16];
      int nt = (c + 127) >> 7;
      for (int m = 0; m < nt; ++m) blockmap[nb++] = (e << 16) | m;
      s += c;
    }
    offsets[E] = s;
    nblk[0] = nb;
  }
}

// ------- scatter: wave-aggregated cursor atomics -------
__global__ void scatter_kernel(const int* __restrict__ topk_e,
                               int* __restrict__ cursor,       // stride 16
                               int* __restrict__ rowtok,
                               int* __restrict__ tokrow) {
  int t = blockIdx.x * 256 + threadIdx.x;   // grid = NTOK/256, exact
  int lane = threadIdx.x & 63;
  unsigned long long lt = ((unsigned long long)1 << lane) - 1;
#pragma unroll
  for (int k = 0; k < 2; ++k) {
    int e = topk_e[2 * t + k];
#pragma unroll
    for (int ee = 0; ee < E; ++ee) {
      unsigned long long m = __ballot(e == ee);
      if (m) {
        int leader = __ffsll((long long)m) - 1;
        int base = 0;
        if (lane == leader) base = atomicAdd(&cursor[ee * 16], __popcll(m));
        base = __shfl(base, leader, 64);
        if (e == ee) {
          int row = base + __popcll(m & lt);
          rowtok[row] = t;
          tokrow[2 * t + k] = row;
        }
      }
    }
  }
}

// -------- batched transpose+cast: fp32 in [batch][R][C] -> bf16 out [batch][C][R] --------
__global__ void transpose_cast_kernel(const float* __restrict__ in, bf16* __restrict__ out,
                                      int R, int C) {
  __shared__ bf16 tile[64][72];
  const float* src = in + (size_t)blockIdx.z * R * C;
  bf16* dst = out + (size_t)blockIdx.z * R * C;
  int c0 = blockIdx.x * 64, r0 = blockIdx.y * 64;
  int tr = threadIdx.x >> 4;          // 0..15
  int tc = (threadIdx.x & 15) * 4;    // 0..60
#pragma unroll
  for (int i = 0; i < 4; ++i) {
    int r = tr + i * 16;
    float4 v = *(const float4*)(src + (size_t)(r0 + r) * C + c0 + tc);
    bf16x4 o;
    o[0] = (bf16)v.x; o[1] = (bf16)v.y; o[2] = (bf16)v.z; o[3] = (bf16)v.w;
    *(bf16x4*)&tile[r][tc] = o;
  }
  __syncthreads();
  int tr2 = threadIdx.x >> 3;         // 0..31
  int tc2 = (threadIdx.x & 7) * 8;    // 0..56
#pragma unroll
  for (int i = 0; i < 2; ++i) {
    int c = tr2 + i * 32;
    bf16x8 v;
#pragma unroll
    for (int j = 0; j < 8; ++j) v[j] = tile[tc2 + j][c];
    *(bf16x8*)(dst + (size_t)(c0 + c) * R + r0 + tc2) = v;
  }
}

// ===== grouped FFN GEMM: 128x128 tile, 4 waves, BK=32, triple-buffer depth-2 =====
// Proven round-1 shell (2 blocks/CU, 0 conflicts, 81us) deepened:
//   - LDS 3 x (A 8KB + B 8KB) = 48KB  -> 3 blocks/CU (12 waves/CU TLP)
//   - prefetch depth 2: stage(t+2) issued at step t; vmcnt(4) leaves stage(t+1)
//     in flight -> every load gets ~2 compute phases of latency cover
//   - ONE barrier per 16-MFMA step (same barrier:MFMA ratio as round 1)
// Hazard proof: stage(t+2) targets buf (t+2)%3 == (t-1)%3; its readers drained at
// step t-1's lgkmcnt(0), which precedes step t's barrier for every wave.
// Swizzle (rule #21, both sides same involution): LDS rows are 64B (32 bf16, 4 x
// 16B segs).  LDS[row][s] holds global k-octet s ^ ((row>>1)&3); granule%8 =
// (row&1)*4 + (s), so 16 consecutive reader lanes cover all 8 bank-granules
// exactly twice (2-way = free, m136).
template <bool GATHER, bool RELU>
__global__ __launch_bounds__(256, 3) void ffn_gemm(
    const bf16* __restrict__ A, const bf16* __restrict__ W,
    const float* __restrict__ bias, bf16* __restrict__ Y,
    const int* __restrict__ rowtok, const int* __restrict__ offsets,
    const int* __restrict__ counts,   // stride 16
    const int* __restrict__ blockmap, const int* __restrict__ nblk,
    int Kdim, int Ndim) {
  // T1: bijective XCD remap (72 % 8 == 0): each XCD owns whole n-strip(s) and
  // sweeps m fastest -> 512KB W panel stays L2-resident per XCD.
  int xcd = blockIdx.x & 7;
  int idx = blockIdx.y * (MAXBLK / 8) + (blockIdx.x >> 3);
  int mIdx = idx % MAXBLK;
  int nIdx = xcd + 8 * (idx / MAXBLK);
  if (mIdx >= nblk[0]) return;   // ghosts
  int bm = blockmap[mIdx];
  int e = bm >> 16;
  int mBase = (bm & 0xffff) << 7;
  int cnt = counts[e * 16];
  int rowBase = offsets[e] + mBase;
  int nBase = nIdx * 128;
  int validRows = cnt - mBase; if (validRows > 128) validRows = 128;

  __shared__ bf16 Asm[3][128][32];   // 24 KB
  __shared__ bf16 Bsm[3][128][32];   // 24 KB

  int tid = threadIdx.x;
  int wave = tid >> 6, lane = tid & 63;

  // ---- staging: wave covers rows [wave*32, wave*32+32) of A and B tiles.
  // gload_lds lane map: row = wave*32 + j*16 + (lane>>2), seg = lane&3.
  // source k-octet = seg ^ ((row>>1)&3) = (lane&3) ^ ((lane>>3)&3).
  int soct = (lane & 3) ^ ((lane >> 3) & 3);
  const bf16 *aP0, *aP1, *bP0, *bP1;
  {
    int r0 = rowBase + wave * 32 + (lane >> 2);
    int r1 = r0 + 16;
    if (r0 > MAXROWS - 1) r0 = MAXROWS - 1;   // partial tile: dup row, masked at store
    if (r1 > MAXROWS - 1) r1 = MAXROWS - 1;
    size_t ro0 = GATHER ? (size_t)rowtok[r0] * Kdim : (size_t)r0 * Kdim;
    size_t ro1 = GATHER ? (size_t)rowtok[r1] * Kdim : (size_t)r1 * Kdim;
    aP0 = A + ro0 + soct * 8;
    aP1 = A + ro1 + soct * 8;
    size_t wb = ((size_t)e * Ndim + nBase + wave * 32 + (lane >> 2)) * (size_t)Kdim;
    bP0 = W + wb + soct * 8;
    bP1 = W + wb + (size_t)16 * Kdim + soct * 8;
  }

  auto stage = [&](int buf, int kc) {   // kc in elements; 4 gloads per wave
    gload_lds16(aP0 + kc, &Asm[buf][wave * 32][0]);
    gload_lds16(aP1 + kc, &Asm[buf][wave * 32 + 16][0]);
    gload_lds16(bP0 + kc, &Bsm[buf][wave * 32][0]);
    gload_lds16(bP1 + kc, &Bsm[buf][wave * 32 + 16][0]);
  };

  // ---- fragment addressing: frag row = lane&15 within each 16-row block;
  // read seg = (lane>>4) ^ ((frow>>1)&3)  (same involution as source)
  int wm = wave & 1, wn = wave >> 1;        // 2x2 wave grid, 64x64 per wave
  int frow = lane & 15;
  int roff = (((lane >> 4) ^ ((frow >> 1) & 3)) << 3);   // element offset in 32-k row

  floatx4 acc[4][4];
#pragma unroll
  for (int m = 0; m < 4; ++m)
#pragma unroll
    for (int n = 0; n < 4; ++n) acc[m][n] = floatx4{0.f, 0.f, 0.f, 0.f};

  int nkt = Kdim >> 5;   // 32-wide K-steps (32 for GEMM1, 64 for GEMM2)

  stage(0, 0);
  stage(1, 32);
  int r = 0;             // buf index = t % 3
  for (int t = 0; t < nkt; ++t) {
    // tile t landed when only stage(t+1)'s 4 loads remain in flight
    if (t + 1 < nkt) asm volatile("s_waitcnt vmcnt(4)" ::: "memory");
    else             asm volatile("s_waitcnt vmcnt(0)" ::: "memory");
    asm volatile("s_barrier" ::: "memory");
    if (t + 2 < nkt) {
      int s = r + 2; if (s >= 3) s -= 3;
      stage(s, (t + 2) * 32);
    }
    bf16x8 af[4], bfr[4];
#pragma unroll
    for (int m = 0; m < 4; ++m)
      af[m] = ds_read16(&Asm[r][wm * 64 + m * 16 + frow][0] + roff);
#pragma unroll
    for (int n = 0; n < 4; ++n)
      bfr[n] = ds_read16(&Bsm[r][wn * 64 + n * 16 + frow][0] + roff);
    asm volatile("s_waitcnt lgkmcnt(0)" ::: "memory");
    __builtin_amdgcn_sched_barrier(0);   // rule #18: MFMAs stay below the lgkm wait
    __builtin_amdgcn_s_setprio(1);
#pragma unroll
    for (int m = 0; m < 4; ++m)
#pragma unroll
      for (int n = 0; n < 4; ++n)
        acc[m][n] = __builtin_amdgcn_mfma_f32_16x16x32_bf16(af[m], bfr[n], acc[m][n], 0, 0, 0);
    __builtin_amdgcn_s_setprio(0);
    ++r; if (r == 3) r = 0;
  }

  // epilogue: C/D layout col=lane&15, row=(lane>>4)*4+reg  [m89-verified]
  int crow = (lane >> 4) * 4;
  int ccol = lane & 15;
#pragma unroll
  for (int n = 0; n < 4; ++n) {
    int colg = nBase + wn * 64 + n * 16 + ccol;
    float bv = bias[(size_t)e * Ndim + colg];
#pragma unroll
    for (int m = 0; m < 4; ++m) {
#pragma unroll
      for (int rr = 0; rr < 4; ++rr) {
        int rl = wm * 64 + m * 16 + crow + rr;
        if (rl < validRows) {
          float v = acc[m][n][rr] + bv;
          if (RELU) v = fmaxf(v, 0.f);
          Y[(size_t)(rowBase + rl) * Ndim + colg] = (bf16)v;
        }
      }
    }
  }
}

// ---------------- combine: out[t] = g0*Y2[r0] + g1*Y2[r1]  (fp32 out) ----------------
__global__ void combine_kernel(const bf16* __restrict__ Y2,
                               const int* __restrict__ tokrow,
                               const float* __restrict__ topk_g,
                               float* __restrict__ out) {
  int idx = blockIdx.x * 256 + threadIdx.x;
  int t = idx >> 7;              // DDIM/8 = 128 vectors per token
  int d8 = (idx & 127) * 8;
  int r0 = tokrow[2 * t], r1 = tokrow[2 * t + 1];
  float g0 = topk_g[2 * t], g1 = topk_g[2 * t + 1];
  bf16x8 a = *(const bf16x8*)(Y2 + (size_t)r0 * DDIM + d8);
  bf16x8 b = *(const bf16x8*)(Y2 + (size_t)r1 * DDIM + d8);
  float o[8];
#pragma unroll
  for (int j = 0; j < 8; ++j) o[j] = g0 * (float)a[j] + g1 * (float)b[j];
  float* op = out + (size_t)t * DDIM + d8;
  *(float4*)op = *(float4*)&o[0];
  *(float4*)(op + 4) = *(float4*)&o[4];
}

}  // namespace

extern "C" void kernel_launch(void* const* d_in, const int* in_sizes, int n_in,
                              void* d_out, int out_size, void* d_ws, size_t ws_size,
                              hipStream_t stream) {
  const float* x  = (const float*)d_in[0];   // [B,T,D] fp32
  const float* Wr = (const float*)d_in[1];   // [D,E]   fp32
  const float* br = (const float*)d_in[2];   // [E]     fp32
  const float* W1 = (const float*)d_in[3];   // [E,D,H] fp32
  const float* b1 = (const float*)d_in[4];   // [E,H]   fp32
  const float* W2 = (const float*)d_in[5];   // [E,H,D] fp32
  const float* b2 = (const float*)d_in[6];   // [E,D]   fp32
  float* out = (float*)d_out;                // [B,T,D] fp32

  char* w = (char*)d_ws;
  int*   counts   = (int*)(w);               // 8 experts, stride 16 ints (64B apart)
  int*   cursor   = (int*)(w + 512);         // 8 experts, stride 16 ints
  int*   offsets  = (int*)(w + 1024);        // 9 ints
  int*   blockmap = (int*)(w + 2048);        // 72 ints
  int*   nblk     = (int*)(w + 2048 + 512);
  int*   topk_e   = (int*)(w + 4096);
  float* topk_g   = (float*)(w + 4096 + 32768);
  int*   rowtok   = (int*)(w + 4096 + 65536);
  int*   tokrow   = (int*)(w + 4096 + 98304);
  char*  big      = w + 4096 + 131072;
  bf16* xb  = (bf16*)(big);                        // [4096][D]  bf16   8.4 MB
  bf16* W1T = (bf16*)(big + 8388608);              // [E][H][D]  bf16  33.5 MB
  bf16* W2T = (bf16*)(big + 8388608 + 33554432);   // [E][D][H]  bf16  33.5 MB
  bf16* Y1  = (bf16*)(big + 8388608 + 67108864);   // [8192][H]  bf16  33.5 MB
  bf16* Y2  = (bf16*)(big + 8388608);              // alias W1T (dead after GEMM1)

  init_kernel<<<1, 128, 0, stream>>>(counts);
  transpose_cast_kernel<<<dim3(HDIM / 64, DDIM / 64, E), 256, 0, stream>>>(W1, W1T, DDIM, HDIM);
  transpose_cast_kernel<<<dim3(DDIM / 64, HDIM / 64, E), 256, 0, stream>>>(W2, W2T, HDIM, DDIM);
  router_kernel<<<NTOK / 8, 256, 0, stream>>>(x, Wr, br, counts, topk_e, topk_g, xb);
  scan_kernel<<<1, 1, 0, stream>>>(counts, offsets, cursor, blockmap, nblk);
  scatter_kernel<<<NTOK / 256, 256, 0, stream>>>(topk_e, cursor, rowtok, tokrow);
  ffn_gemm<true, true><<<dim3(MAXBLK, HDIM / 128), 256, 0, stream>>>(
      xb, W1T, b1, Y1, rowtok, offsets, counts, blockmap, nblk, DDIM, HDIM);
  ffn_gemm<false, false><<<dim3(MAXBLK, DDIM / 128), 256, 0, stream>>>(
      Y1, W2T, b2, Y2, rowtok, offsets, counts, blockmap, nblk, HDIM, DDIM);
  combine_kernel<<<NTOK * DDIM / 8 / 256, 256, 0, stream>>>(Y2, tokrow, topk_g, out);
}